// Round 1
// baseline (285.422 us; speedup 1.0000x reference)
//
#include <hip/hip_runtime.h>
#include <hip/hip_bf16.h>
#include <math.h>

typedef __bf16 bf16;
typedef __bf16 bf16x4 __attribute__((ext_vector_type(4)));
typedef __bf16 bf16x8 __attribute__((ext_vector_type(8)));
typedef float f32x4 __attribute__((ext_vector_type(4)));
typedef unsigned int u32;
typedef u32 __attribute__((address_space(1))) gu32;
typedef u32 __attribute__((address_space(3))) lu32;

#define TOK   16384
#define D_    256
#define HD    2048
#define QKVN  6144

#define GLDS16(g, l) __builtin_amdgcn_global_load_lds((gu32*)(g), (lu32*)(l), 16, 0, 0)

// ---------------------------------------------------------------------------
// ONE prep kernel: roles by blockIdx.x. Dtype flag computed block-locally.
//   b <  4096: convert x (4 elems/thread)
//   b <  4121: biases bq|bk|bv -> bqkv, bo -> bob
//   b <  5657: transpose Wq/Wk/Wv (256x2048 -> 2048x256)
//   b <  6169: transpose Wo (2048x256 -> 256x2048) with K permuted to
//              d-major: WoT[n][d*8+h] = Wo[h*256+d][n]  (for out_fused)
// ---------------------------------------------------------------------------
__device__ __forceinline__ void transpose_body(
    const void* __restrict__ src, bf16* __restrict__ dst, int R, int C,
    int tc, int tr, int f, int perm, float (*tile)[33])
{
    int lx = threadIdx.x & 31, ly = threadIdx.x >> 5;
    for (int i = 0; i < 4; i++) {
        int r = ly + i * 8;
        size_t idx = (size_t)(tr + r) * C + tc + lx;
        tile[r][lx] = f ? ((const float*)src)[idx] : (float)((const bf16*)src)[idx];
    }
    __syncthreads();
    for (int i = 0; i < 4; i++) {
        int r = ly + i * 8;
        int k = tr + lx;                     // K index of the transposed elem
        size_t di = perm
            ? (size_t)(tc + r) * R + (size_t)(k & 255) * 8 + (k >> 8)
            : (size_t)(tc + r) * R + k;
        dst[di] = (bf16)tile[lx][r];
    }
}

__global__ __launch_bounds__(256) void prep(
    const void* __restrict__ x,
    const void* __restrict__ Wq, const void* __restrict__ bq,
    const void* __restrict__ Wk, const void* __restrict__ bk,
    const void* __restrict__ Wv, const void* __restrict__ bv,
    const void* __restrict__ Wo, const void* __restrict__ bo,
    bf16* __restrict__ xb, bf16* __restrict__ WT, bf16* __restrict__ WoT,
    bf16* __restrict__ bqkv, bf16* __restrict__ bob)
{
    __shared__ float tile[32][33];
    __shared__ int sflag;
    int tid = threadIdx.x;
    if (tid == 0) sflag = 0;
    __syncthreads();
    {
        float v = fabsf((float)((const bf16*)x)[2 * tid]);
        if (!(v < 1e4f)) sflag = 1;   // benign race, all writers store 1
    }
    __syncthreads();
    int f = sflag;
    int b = blockIdx.x;

    if (b < 4096) {                               // convert x
        int i = b * 256 + tid;
        bf16x4 o;
        if (f) { f32x4 v = ((const f32x4*)x)[i]; for (int e = 0; e < 4; e++) o[e] = (bf16)v[e]; }
        else   { o = ((const bf16x4*)x)[i]; }
        ((bf16x4*)xb)[i] = o;
    } else if (b < 4121) {                        // biases
        int i = (b - 4096) * 256 + tid;
        if (i < 6400) {
            const void* src; bf16* dst; int off;
            if (i < 2048)      { src = bq; dst = bqkv;        off = i; }
            else if (i < 4096) { src = bk; dst = bqkv + 2048; off = i - 2048; }
            else if (i < 6144) { src = bv; dst = bqkv + 4096; off = i - 4096; }
            else               { src = bo; dst = bob;         off = i - 6144; }
            float v = f ? ((const float*)src)[off] : (float)((const bf16*)src)[off];
            dst[off] = (bf16)v;
        }
        __syncthreads();                          // match transpose barrier count
    } else if (b < 5657) {                        // Wq/Wk/Wv transpose
        int idx = b - 4121;                       // 0..1535
        int tx = idx & 63, rest = idx >> 6;
        int ty = rest & 7, tz = rest >> 3;
        const void* src = (tz == 0) ? Wq : (tz == 1) ? Wk : Wv;
        bf16* dst = WT + (size_t)tz * 2048 * 256;
        transpose_body(src, dst, 256, 2048, tx * 32, ty * 32, f, 0, tile);
    } else {                                      // Wo transpose + K-permute
        int idx = b - 5657;                       // 0..511
        int tx = idx & 7, ty = idx >> 3;
        transpose_body(Wo, WoT, 2048, 256, tx * 32, ty * 32, f, 1, tile);
    }
}

// ---------------------------------------------------------------------------
// Kernel 1: qkv = x @ [Wq|Wk|Wv] + bias  (unchanged — pinned at write floor)
// ---------------------------------------------------------------------------
__global__ __launch_bounds__(256) void proj_gemm(
    const bf16* __restrict__ X, const bf16* __restrict__ WT,
    const bf16* __restrict__ bqkv, bf16* __restrict__ qkv)
{
    __shared__ char smem[36864];               // union: As+Bs (32K) / epi (36K)
    bf16* As = (bf16*)smem;                    // 128*64
    bf16* Bs = (bf16*)(smem + 16384);          // 128*64
    int m0 = blockIdx.y * 128, n0 = blockIdx.x * 128;
    int tid = threadIdx.x, wave = tid >> 6, lane = tid & 63;
    int wm = (wave >> 1) * 64, wn = (wave & 1) * 64;
    int mrow = lane & 15, quad = lane >> 4;
    int lrow8 = lane >> 3, lslot = lane & 7;

    f32x4 acc[4][4] = {};
    for (int k0 = 0; k0 < D_; k0 += 64) {
        __syncthreads();
        for (int i = 0; i < 4; i++) {
            int rbase = wave * 32 + i * 8;
            int row = rbase + lrow8;
            int gc = lslot ^ (row & 7);
            GLDS16(&X[(size_t)(m0 + row) * D_ + k0 + gc * 8], &As[rbase * 64]);
            GLDS16(&WT[(size_t)(n0 + row) * D_ + k0 + gc * 8], &Bs[rbase * 64]);
        }
        __syncthreads();
        for (int kk = 0; kk < 64; kk += 32) {
            int slot = (((kk >> 3) + quad) ^ (mrow & 7)) * 8;
            bf16x8 af[4], bfv[4];
            for (int mt = 0; mt < 4; mt++)
                af[mt] = *(const bf16x8*)&As[(wm + mt * 16 + mrow) * 64 + slot];
            for (int nt = 0; nt < 4; nt++)
                bfv[nt] = *(const bf16x8*)&Bs[(wn + nt * 16 + mrow) * 64 + slot];
            for (int mt = 0; mt < 4; mt++)
                for (int nt = 0; nt < 4; nt++)
                    acc[mt][nt] = __builtin_amdgcn_mfma_f32_16x16x32_bf16(
                        bfv[nt], af[mt], acc[mt][nt], 0, 0, 0);
        }
    }

    __syncthreads();
    bf16* ep = (bf16*)smem + wave * (64 * 72);
    for (int mt = 0; mt < 4; mt++) {
        for (int nt = 0; nt < 4; nt++) {
            int col = n0 + wn + nt * 16 + quad * 4;
            bf16x4 bb = *(const bf16x4*)&bqkv[col];
            bf16x4 o;
            for (int r = 0; r < 4; r++) o[r] = (bf16)(acc[mt][nt][r] + (float)bb[r]);
            *(bf16x4*)&ep[(mt * 16 + mrow) * 72 + nt * 16 + quad * 4] = o;
        }
    }
    __syncthreads();
    for (int i = 0; i < 8; i++) {
        int r = i * 8 + (lane >> 3);
        int cb = (lane & 7) * 8;
        bf16x8 val = *(const bf16x8*)&ep[r * 72 + cb];
        *(bf16x8*)&qkv[(size_t)(m0 + wm + r) * QKVN + n0 + wn + cb] = val;
    }
}

// ---------------------------------------------------------------------------
// Kernel 2: per-token 8x8 softmax probabilities ONLY.
// Reads q,k (134 MB), writes P (16384x64 f32 = 4 MB). No LDS, no barriers:
// lane (h,g) dots q_h . k_g straight from global (8 lanes share each 16B
// address -> HW coalesces to 128 B/instr, no duplication).
// grid 1024 x 256: 4096 waves x 4 tokens.
// ---------------------------------------------------------------------------
__global__ __launch_bounds__(256) void attn_score(
    const bf16* __restrict__ qkv, float* __restrict__ P)
{
    int wave = threadIdx.x >> 6, lane = threadIdx.x & 63;
    int h = lane >> 3, g = lane & 7;
    int wid = blockIdx.x * 4 + wave;               // 0..4095
    for (int ti = 0; ti < 4; ti++) {
        int t = wid * 4 + ti;
        const bf16* qrow = qkv + (size_t)t * QKVN + h * 256;
        const bf16* krow = qkv + (size_t)t * QKVN + 2048 + g * 256;
        float s0 = 0.f, s1 = 0.f, s2 = 0.f, s3 = 0.f;
#pragma unroll
        for (int c = 0; c < 32; c += 4) {
            bf16x8 a0 = *(const bf16x8*)&qrow[(c + 0) * 8];
            bf16x8 b0 = *(const bf16x8*)&krow[(c + 0) * 8];
            bf16x8 a1 = *(const bf16x8*)&qrow[(c + 1) * 8];
            bf16x8 b1 = *(const bf16x8*)&krow[(c + 1) * 8];
            bf16x8 a2 = *(const bf16x8*)&qrow[(c + 2) * 8];
            bf16x8 b2 = *(const bf16x8*)&krow[(c + 2) * 8];
            bf16x8 a3 = *(const bf16x8*)&qrow[(c + 3) * 8];
            bf16x8 b3 = *(const bf16x8*)&krow[(c + 3) * 8];
            for (int e = 0; e < 8; e++) {
                s0 += (float)a0[e] * (float)b0[e];
                s1 += (float)a1[e] * (float)b1[e];
                s2 += (float)a2[e] * (float)b2[e];
                s3 += (float)a3[e] * (float)b3[e];
            }
        }
        float s = ((s0 + s1) + (s2 + s3)) * 0.0625f;
        float m = s;
        for (int off = 1; off < 8; off <<= 1) m = fmaxf(m, __shfl_xor(m, off, 8));
        float p = __expf(s - m);
        float sum = p;
        for (int off = 1; off < 8; off <<= 1) sum += __shfl_xor(sum, off, 8);
        P[(size_t)t * 64 + lane] = p / sum;
    }
}

// ---------------------------------------------------------------------------
// Kernel 3: out = (P @ v) @ Wo' + bo, attnout never touches HBM.
// Per block: 32 tokens x full N=256. K' = d*8+h (d-major, matches permuted
// WoT). Per K'-chunk of 64 (= 8 d-values x 8 heads):
//   - stage v slice [32t][8g][8d] (4 KB, g XOR-swizzled via global addr)
//   - stage Wo' slice [256n][64k] (32 KB, row XOR-swizzled)
//   - thread (t,dof) computes attnout[t][(d0+dof)*8 + h], h=0..7, from its
//     register-resident P row -> one bf16x8 ds_write into As (slot-swizzled)
//   - 16 MFMA/wave vs Bs  (layouts identical to the verified out_gemm)
// LDS 40 KB -> 4 blocks/CU by LDS. HBM: v 67 MB + P 4 MB in, out 16.7 MB.
// ---------------------------------------------------------------------------
__global__ __launch_bounds__(256) void out_fused(
    const bf16* __restrict__ qkv, const bf16* __restrict__ WoT,
    const float* __restrict__ P, const bf16* __restrict__ bob,
    float* __restrict__ outp)
{
    __shared__ bf16 Bs[256 * 64];   // 32 KB  Wo' chunk
    __shared__ bf16 As[32 * 64];    // 4 KB   attnout chunk
    __shared__ bf16 Vs[32 * 64];    // 4 KB   v chunk
    int m0 = blockIdx.x * 32;
    int tid = threadIdx.x, wave = tid >> 6, lane = tid & 63;
    int wm = (wave >> 1) * 16, wn = (wave & 1) * 128;
    int mrow = lane & 15, quad = lane >> 4;

    // attnout producer mapping: thread <-> (token t, d-offset dof)
    int t = tid >> 3, dof = tid & 7, ts = t & 7;
    // staging lane decode (wave-local)
    int sl_t8 = lane >> 3, sl_g = lane & 7;

    // P row (64 probs, h-major) into registers. 8 lanes share each address.
    float Pv[64];
    {
        const float* pr = P + (size_t)(m0 + t) * 64;
#pragma unroll
        for (int j = 0; j < 16; j++) {
            f32x4 v4 = *(const f32x4*)&pr[j * 4];
            Pv[j * 4 + 0] = v4[0]; Pv[j * 4 + 1] = v4[1];
            Pv[j * 4 + 2] = v4[2]; Pv[j * 4 + 3] = v4[3];
        }
    }

    f32x4 acc[8] = {};
    for (int c = 0; c < 32; c++) {
        __syncthreads();                        // prev chunk fully consumed
        {   // stage Vs: wave w -> tokens w*8..w*8+7; position p holds g=p^(t&7)
            int tt = wave * 8 + sl_t8;
            int gg = sl_g ^ (tt & 7);
            GLDS16(&qkv[(size_t)(m0 + tt) * QKVN + 4096 + gg * 256 + c * 8],
                   &Vs[wave * 512]);
        }
#pragma unroll
        for (int i = 0; i < 8; i++) {           // stage Bs: wave w -> rows w*64..+63
            int n = wave * 64 + i * 8 + sl_t8;
            int gc = sl_g ^ (n & 7);
            GLDS16(&WoT[(size_t)n * HD + c * 64 + gc * 8],
                   &Bs[(wave * 64 + i * 8) * 64]);
        }
        __syncthreads();                        // stages resident (vmcnt drained)
        {   // attnout: 8 outputs (h=0..7) for (t, d = c*8+dof)
            float vf[8];
#pragma unroll
            for (int g = 0; g < 8; g++)
                vf[g] = (float)Vs[t * 64 + ((g ^ ts) << 3) + dof];
            bf16x8 ao;
#pragma unroll
            for (int h = 0; h < 8; h++) {
                float a = 0.f;
#pragma unroll
                for (int g = 0; g < 8; g++) a += Pv[h * 8 + g] * vf[g];
                ao[h] = (bf16)a;
            }
            *(bf16x8*)&As[t * 64 + ((dof ^ ts) << 3)] = ao;
        }
        __syncthreads();                        // As visible
#pragma unroll
        for (int kk = 0; kk < 64; kk += 32) {
            int slot = (((kk >> 3) + quad) ^ (mrow & 7)) * 8;
            bf16x8 af = *(const bf16x8*)&As[(wm + mrow) * 64 + slot];
#pragma unroll
            for (int nt = 0; nt < 8; nt++) {
                bf16x8 bv = *(const bf16x8*)&Bs[(wn + nt * 16 + mrow) * 64 + slot];
                acc[nt] = __builtin_amdgcn_mfma_f32_16x16x32_bf16(bv, af, acc[nt], 0, 0, 0);
            }
        }
    }

    int row = m0 + wm + mrow;
#pragma unroll
    for (int nt = 0; nt < 8; nt++) {
        int col = wn + nt * 16 + quad * 4;
        bf16x4 bb = *(const bf16x4*)&bob[col];
        f32x4 o;
        for (int r = 0; r < 4; r++) o[r] = acc[nt][r] + (float)bb[r];
        *(f32x4*)&outp[(size_t)row * D_ + col] = o;
    }
}

// ---------------------------------------------------------------------------
extern "C" void kernel_launch(void* const* d_in, const int* in_sizes, int n_in,
                              void* d_out, int out_size, void* d_ws, size_t ws_size,
                              hipStream_t stream)
{
    const void* x  = d_in[0];
    const void* Wq = d_in[1];
    const void* bq = d_in[2];
    const void* Wk = d_in[3];
    const void* bk = d_in[4];
    const void* Wv = d_in[5];
    const void* bv = d_in[6];
    const void* Wo = d_in[7];
    const void* bo = d_in[8];
    float* out = (float*)d_out;

    char* ws = (char*)d_ws;
    bf16* qkv  = (bf16*)ws;                          // 201326592 B
    bf16* WT   = (bf16*)(ws + 201326592);            // 3145728 B
    bf16* WoT  = (bf16*)(ws + 204472320);            // 1048576 B
    bf16* xb   = (bf16*)(ws + 205520896);            // 8388608 B
    bf16* bqkv = (bf16*)(ws + 213909504);            // 12288 B
    bf16* bob  = (bf16*)(ws + 213921792);            // 512 B
    // P (16384*64 f32 = 4 MB) reuses the xb region: xb is dead after
    // proj_gemm, and attn_score runs strictly after it on the same stream.
    float* Pbuf = (float*)xb;

    prep<<<6169, 256, 0, stream>>>(x, Wq, bq, Wk, bk, Wv, bv, Wo, bo,
                                   xb, WT, WoT, bqkv, bob);
    proj_gemm<<<dim3(48, 128), 256, 0, stream>>>(xb, WT, bqkv, qkv);
    attn_score<<<1024, 256, 0, stream>>>(qkv, Pbuf);
    out_fused<<<512, 256, 0, stream>>>(qkv, WoT, Pbuf, bob, out);
}

// Round 2
// 235.010 us; speedup vs baseline: 1.2145x; 1.2145x over previous
//
#include <hip/hip_runtime.h>
#include <hip/hip_bf16.h>
#include <math.h>

typedef __bf16 bf16;
typedef __bf16 bf16x4 __attribute__((ext_vector_type(4)));
typedef __bf16 bf16x8 __attribute__((ext_vector_type(8)));
typedef float f32x4 __attribute__((ext_vector_type(4)));
typedef unsigned int u32;
typedef u32 __attribute__((address_space(1))) gu32;
typedef u32 __attribute__((address_space(3))) lu32;

#define TOK   16384
#define D_    256
#define HD    2048
#define QKVN  6144

#define GLDS16(g, l) __builtin_amdgcn_global_load_lds((gu32*)(g), (lu32*)(l), 16, 0, 0)
// s_waitcnt imm: vmcnt[3:0] | expcnt<<4 | lgkmcnt<<8  (expcnt=7,lgkm=15 -> no wait)
#define WAIT_VM(n) __builtin_amdgcn_s_waitcnt(0x0F70 | (n))

// ---------------------------------------------------------------------------
// ONE prep kernel: roles by blockIdx.x. Dtype flag computed block-locally.
//   b <  4096: convert x (4 elems/thread)
//   b <  4121: biases bq|bk|bv -> bqkv (v part d-major permuted), bo -> bob
//   b <  5657: transpose Wq/Wk/Wv (256x2048 -> 2048x256); Wv rows permuted
//              to d-major (n' = (n&255)*8 + n>>8) so qkv's v block is d-major
//   b <  6169: transpose Wo (2048x256 -> 256x2048) with K permuted to
//              d-major: WoT[n][d*8+h] = Wo[h*256+d][n]  (for out_fused)
// ---------------------------------------------------------------------------
__device__ __forceinline__ void transpose_body(
    const void* __restrict__ src, bf16* __restrict__ dst, int R, int C,
    int tc, int tr, int f, int mode, float (*tile)[33])
{
    int lx = threadIdx.x & 31, ly = threadIdx.x >> 5;
    for (int i = 0; i < 4; i++) {
        int r = ly + i * 8;
        size_t idx = (size_t)(tr + r) * C + tc + lx;
        tile[r][lx] = f ? ((const float*)src)[idx] : (float)((const bf16*)src)[idx];
    }
    __syncthreads();
    for (int i = 0; i < 4; i++) {
        int r = ly + i * 8;
        int k = tr + lx;                     // K index of the transposed elem
        int n = tc + r;                      // output row
        size_t di;
        if (mode == 1)      di = (size_t)n * R + (size_t)(k & 255) * 8 + (k >> 8);
        else if (mode == 2) di = (size_t)(((n & 255) << 3) | (n >> 8)) * R + k;
        else                di = (size_t)n * R + k;
        dst[di] = (bf16)tile[lx][r];
    }
}

__global__ __launch_bounds__(256) void prep(
    const void* __restrict__ x,
    const void* __restrict__ Wq, const void* __restrict__ bq,
    const void* __restrict__ Wk, const void* __restrict__ bk,
    const void* __restrict__ Wv, const void* __restrict__ bv,
    const void* __restrict__ Wo, const void* __restrict__ bo,
    bf16* __restrict__ xb, bf16* __restrict__ WT, bf16* __restrict__ WoT,
    bf16* __restrict__ bqkv, bf16* __restrict__ bob)
{
    __shared__ float tile[32][33];
    __shared__ int sflag;
    int tid = threadIdx.x;
    if (tid == 0) sflag = 0;
    __syncthreads();
    {
        float v = fabsf((float)((const bf16*)x)[2 * tid]);
        if (!(v < 1e4f)) sflag = 1;   // benign race, all writers store 1
    }
    __syncthreads();
    int f = sflag;
    int b = blockIdx.x;

    if (b < 4096) {                               // convert x
        int i = b * 256 + tid;
        bf16x4 o;
        if (f) { f32x4 v = ((const f32x4*)x)[i]; for (int e = 0; e < 4; e++) o[e] = (bf16)v[e]; }
        else   { o = ((const bf16x4*)x)[i]; }
        ((bf16x4*)xb)[i] = o;
    } else if (b < 4121) {                        // biases
        int i = (b - 4096) * 256 + tid;
        if (i < 6400) {
            const void* src; bf16* dst; int off, woff;
            if (i < 2048)      { src = bq; dst = bqkv;        off = i;        woff = off; }
            else if (i < 4096) { src = bk; dst = bqkv + 2048; off = i - 2048; woff = off; }
            else if (i < 6144) { src = bv; dst = bqkv + 4096; off = i - 4096;
                                 woff = ((off & 255) << 3) | (off >> 8); }    // d-major
            else               { src = bo; dst = bob;         off = i - 6144; woff = off; }
            float v = f ? ((const float*)src)[off] : (float)((const bf16*)src)[off];
            dst[woff] = (bf16)v;
        }
        __syncthreads();                          // match transpose barrier count
    } else if (b < 5657) {                        // Wq/Wk/Wv transpose
        int idx = b - 4121;                       // 0..1535
        int tx = idx & 63, rest = idx >> 6;
        int ty = rest & 7, tz = rest >> 3;
        const void* src = (tz == 0) ? Wq : (tz == 1) ? Wk : Wv;
        bf16* dst = WT + (size_t)tz * 2048 * 256;
        transpose_body(src, dst, 256, 2048, tx * 32, ty * 32, f, (tz == 2) ? 2 : 0, tile);
    } else {                                      // Wo transpose + K-permute
        int idx = b - 5657;                       // 0..511
        int tx = idx & 7, ty = idx >> 3;
        transpose_body(Wo, WoT, 2048, 256, tx * 32, ty * 32, f, 1, tile);
    }
}

// ---------------------------------------------------------------------------
// Kernel 1: qkv = x @ [Wq|Wk|Wv] + bias  (unchanged — pinned at write floor)
// ---------------------------------------------------------------------------
__global__ __launch_bounds__(256) void proj_gemm(
    const bf16* __restrict__ X, const bf16* __restrict__ WT,
    const bf16* __restrict__ bqkv, bf16* __restrict__ qkv)
{
    __shared__ char smem[36864];               // union: As+Bs (32K) / epi (36K)
    bf16* As = (bf16*)smem;                    // 128*64
    bf16* Bs = (bf16*)(smem + 16384);          // 128*64
    int m0 = blockIdx.y * 128, n0 = blockIdx.x * 128;
    int tid = threadIdx.x, wave = tid >> 6, lane = tid & 63;
    int wm = (wave >> 1) * 64, wn = (wave & 1) * 64;
    int mrow = lane & 15, quad = lane >> 4;
    int lrow8 = lane >> 3, lslot = lane & 7;

    f32x4 acc[4][4] = {};
    for (int k0 = 0; k0 < D_; k0 += 64) {
        __syncthreads();
        for (int i = 0; i < 4; i++) {
            int rbase = wave * 32 + i * 8;
            int row = rbase + lrow8;
            int gc = lslot ^ (row & 7);
            GLDS16(&X[(size_t)(m0 + row) * D_ + k0 + gc * 8], &As[rbase * 64]);
            GLDS16(&WT[(size_t)(n0 + row) * D_ + k0 + gc * 8], &Bs[rbase * 64]);
        }
        __syncthreads();
        for (int kk = 0; kk < 64; kk += 32) {
            int slot = (((kk >> 3) + quad) ^ (mrow & 7)) * 8;
            bf16x8 af[4], bfv[4];
            for (int mt = 0; mt < 4; mt++)
                af[mt] = *(const bf16x8*)&As[(wm + mt * 16 + mrow) * 64 + slot];
            for (int nt = 0; nt < 4; nt++)
                bfv[nt] = *(const bf16x8*)&Bs[(wn + nt * 16 + mrow) * 64 + slot];
            for (int mt = 0; mt < 4; mt++)
                for (int nt = 0; nt < 4; nt++)
                    acc[mt][nt] = __builtin_amdgcn_mfma_f32_16x16x32_bf16(
                        bfv[nt], af[mt], acc[mt][nt], 0, 0, 0);
        }
    }

    __syncthreads();
    bf16* ep = (bf16*)smem + wave * (64 * 72);
    for (int mt = 0; mt < 4; mt++) {
        for (int nt = 0; nt < 4; nt++) {
            int col = n0 + wn + nt * 16 + quad * 4;
            bf16x4 bb = *(const bf16x4*)&bqkv[col];
            bf16x4 o;
            for (int r = 0; r < 4; r++) o[r] = (bf16)(acc[mt][nt][r] + (float)bb[r]);
            *(bf16x4*)&ep[(mt * 16 + mrow) * 72 + nt * 16 + quad * 4] = o;
        }
    }
    __syncthreads();
    for (int i = 0; i < 8; i++) {
        int r = i * 8 + (lane >> 3);
        int cb = (lane & 7) * 8;
        bf16x8 val = *(const bf16x8*)&ep[r * 72 + cb];
        *(bf16x8*)&qkv[(size_t)(m0 + wm + r) * QKVN + n0 + wn + cb] = val;
    }
}

// ---------------------------------------------------------------------------
// Kernel 2: per-token 8x8 softmax probabilities (LDS-staged, double-buffered).
// Per wave: stage q+k (8 KB, 8x GLDS16 coalesced, XOR-swizzled) for token
// t+1 while computing token t (counted WAIT_VM(8) keeps 8 loads in flight).
// 512 blocks x 4 waves x 8 tokens; 64 KB LDS -> 2 blocks/CU, all resident.
// Reads q,k (134 MB) coalesced; writes P (4 MB fp32).
// ---------------------------------------------------------------------------
__device__ __forceinline__ void stage_qk(const bf16* __restrict__ qkv,
                                         bf16* dstb, int t, int lane)
{
    const bf16* base = qkv + (size_t)t * QKVN;
#pragma unroll
    for (int i = 0; i < 8; i++) {
        int s = i * 64 + lane;
        int row = s >> 5, cs = s & 31;
        int gc = cs ^ (row & 7);
        GLDS16(base + row * 256 + gc * 8, (char*)dstb + i * 1024);
    }
}

__global__ __launch_bounds__(256) void attn_score(
    const bf16* __restrict__ qkv, float* __restrict__ P)
{
    __shared__ bf16 sh[4][2][4096];   // per wave x 2 buffers: rows 0-7 q, 8-15 k
    int wave = threadIdx.x >> 6, lane = threadIdx.x & 63;
    int h = lane >> 3, g = lane & 7;
    int wid = blockIdx.x * 4 + wave;               // 0..2047
    int t0 = wid * 8;

    stage_qk(qkv, sh[wave][0], t0, lane);
    for (int ti = 0; ti < 8; ti++) {
        if (ti < 7) {
            stage_qk(qkv, sh[wave][(ti + 1) & 1], t0 + ti + 1, lane);
            WAIT_VM(8);          // token ti's 8 loads done; ti+1's in flight
        } else {
            WAIT_VM(0);
        }
        const bf16* buf = sh[wave][ti & 1];
        const bf16* qrow = buf + h * 256;
        const bf16* krow = buf + (8 + g) * 256;
        float s0 = 0.f, s1 = 0.f, s2 = 0.f, s3 = 0.f;
        for (int c = 0; c < 32; c += 4) {
            bf16x8 a0 = *(const bf16x8*)&qrow[((c + 0) ^ h) * 8];
            bf16x8 b0 = *(const bf16x8*)&krow[((c + 0) ^ g) * 8];
            bf16x8 a1 = *(const bf16x8*)&qrow[((c + 1) ^ h) * 8];
            bf16x8 b1 = *(const bf16x8*)&krow[((c + 1) ^ g) * 8];
            bf16x8 a2 = *(const bf16x8*)&qrow[((c + 2) ^ h) * 8];
            bf16x8 b2 = *(const bf16x8*)&krow[((c + 2) ^ g) * 8];
            bf16x8 a3 = *(const bf16x8*)&qrow[((c + 3) ^ h) * 8];
            bf16x8 b3 = *(const bf16x8*)&krow[((c + 3) ^ g) * 8];
            for (int e = 0; e < 8; e++) {
                s0 += (float)a0[e] * (float)b0[e];
                s1 += (float)a1[e] * (float)b1[e];
                s2 += (float)a2[e] * (float)b2[e];
                s3 += (float)a3[e] * (float)b3[e];
            }
        }
        float s = ((s0 + s1) + (s2 + s3)) * 0.0625f;
        float m = s;
        for (int off = 1; off < 8; off <<= 1) m = fmaxf(m, __shfl_xor(m, off, 8));
        float p = __expf(s - m);
        float sum = p;
        for (int off = 1; off < 8; off <<= 1) sum += __shfl_xor(sum, off, 8);
        P[(size_t)(t0 + ti) * 64 + lane] = p / sum;
    }
}

// ---------------------------------------------------------------------------
// Kernel 3: out = (P @ v) @ Wo' + bo, attnout never in LDS OR HBM.
// v is d-major (qkv col 4096 + d*8 + g), Wo' K is d-major -> the A-fragment
// lane (mrow,quad) needs for MFMA kk is exactly:
//   af[j] = sum_g P[t, j*8+g] * v[t, g, d=c*8+quad+(kk?4:0)],  t = wm+mrow
// i.e. one bf16x8 Vs read + 8 dot-8s against the register-resident P row,
// computed IN the consuming lane: no As buffer, no producer barrier.
// Double-buffered Vs+Bs (72 KB, 2 blocks/CU), ONE barrier per chunk, stage
// loads for chunk c+1 in flight across chunk c's compute.
// HBM: v 67 MB + P 4 MB in, out 16.7 MB. WoT re-reads served by L2.
// ---------------------------------------------------------------------------
__global__ __launch_bounds__(256) void out_fused(
    const bf16* __restrict__ qkv, const bf16* __restrict__ WoT,
    const float* __restrict__ P, const bf16* __restrict__ bob,
    float* __restrict__ outp)
{
    __shared__ bf16 Bs[2][256 * 64];   // 64 KB  Wo' chunk (double)
    __shared__ bf16 Vs[2][32 * 64];    // 8 KB   v chunk (double)
    int m0 = blockIdx.x * 32;
    int tid = threadIdx.x, wave = tid >> 6, lane = tid & 63;
    int wm = (wave >> 1) * 16, wn = (wave & 1) * 128;
    int mrow = lane & 15, quad = lane >> 4;
    int t = wm + mrow, ts = t & 7;     // block-local token this lane owns
    int sl8 = lane >> 3, sl = lane & 7;

    // P row (64 probs, h-major) into registers; 4 lanes share each row.
    float Pv[64];
    {
        const float* pr = P + (size_t)(m0 + t) * 64;
#pragma unroll
        for (int j = 0; j < 16; j++) {
            f32x4 v4 = *(const f32x4*)&pr[j * 4];
            Pv[4 * j + 0] = v4[0]; Pv[4 * j + 1] = v4[1];
            Pv[4 * j + 2] = v4[2]; Pv[4 * j + 3] = v4[3];
        }
    }

#define STAGE(bb, cc) {                                                        \
        int tt = (wave << 3) + sl8;                                            \
        GLDS16(&qkv[(size_t)(m0 + tt) * QKVN + 4096 + (cc) * 64                \
                    + ((sl ^ (tt & 7)) << 3)], &Vs[bb][wave * 512]);           \
        for (int i = 0; i < 8; i++) {                                          \
            int n = (wave << 6) + (i << 3) + sl8;                              \
            GLDS16(&WoT[(size_t)n * HD + (cc) * 64 + ((sl ^ (n & 7)) << 3)],   \
                   &Bs[bb][(wave << 6) + (i << 3) << 6]);                      \
        } }

    f32x4 acc[8] = {};
    {   // prologue: stage chunk 0
        int tt = (wave << 3) + sl8;
        GLDS16(&qkv[(size_t)(m0 + tt) * QKVN + 4096 + ((sl ^ (tt & 7)) << 3)],
               &Vs[0][wave * 512]);
#pragma unroll
        for (int i = 0; i < 8; i++) {
            int n = (wave << 6) + (i << 3) + sl8;
            GLDS16(&WoT[(size_t)n * HD + ((sl ^ (n & 7)) << 3)],
                   &Bs[0][((wave << 6) + (i << 3)) << 6]);
        }
    }

    for (int c = 0; c < 32; c++) {
        __syncthreads();               // buf[c&1] resident (barrier drains vmcnt)
        if (c < 31) {                  // stage chunk c+1 (in flight across compute)
            int cc = c + 1, bb = cc & 1;
            int tt = (wave << 3) + sl8;
            GLDS16(&qkv[(size_t)(m0 + tt) * QKVN + 4096 + cc * 64
                        + ((sl ^ (tt & 7)) << 3)], &Vs[bb][wave * 512]);
#pragma unroll
            for (int i = 0; i < 8; i++) {
                int n = (wave << 6) + (i << 3) + sl8;
                GLDS16(&WoT[(size_t)n * HD + cc * 64 + ((sl ^ (n & 7)) << 3)],
                       &Bs[bb][((wave << 6) + (i << 3)) << 6]);
            }
        }
        const bf16* Vb = Vs[c & 1];
        const bf16* Bb = Bs[c & 1];

        // producer-in-lane: A-fragments for kk=0 (d-chunk quad) and kk=32 (quad+4)
        bf16x8 vf0 = *(const bf16x8*)&Vb[(t << 6) + ((quad ^ ts) << 3)];
        bf16x8 vf1 = *(const bf16x8*)&Vb[(t << 6) + (((quad + 4) ^ ts) << 3)];
        float v0f[8], v1f[8];
#pragma unroll
        for (int e = 0; e < 8; e++) { v0f[e] = (float)vf0[e]; v1f[e] = (float)vf1[e]; }
        bf16x8 af0, af1;
#pragma unroll
        for (int hh = 0; hh < 8; hh++) {
            float a0 = 0.f, a1 = 0.f;
#pragma unroll
            for (int gg = 0; gg < 8; gg++) {
                a0 += Pv[hh * 8 + gg] * v0f[gg];
                a1 += Pv[hh * 8 + gg] * v1f[gg];
            }
            af0[hh] = (bf16)a0; af1[hh] = (bf16)a1;
        }
#pragma unroll
        for (int nt = 0; nt < 8; nt++) {
            bf16x8 bv = *(const bf16x8*)&Bb[(wn + nt * 16 + mrow) * 64
                            + ((quad ^ (mrow & 7)) << 3)];
            acc[nt] = __builtin_amdgcn_mfma_f32_16x16x32_bf16(bv, af0, acc[nt], 0, 0, 0);
        }
#pragma unroll
        for (int nt = 0; nt < 8; nt++) {
            bf16x8 bv = *(const bf16x8*)&Bb[(wn + nt * 16 + mrow) * 64
                            + (((4 + quad) ^ (mrow & 7)) << 3)];
            acc[nt] = __builtin_amdgcn_mfma_f32_16x16x32_bf16(bv, af1, acc[nt], 0, 0, 0);
        }
    }
#undef STAGE

    int row = m0 + wm + mrow;
#pragma unroll
    for (int nt = 0; nt < 8; nt++) {
        int col = wn + nt * 16 + quad * 4;
        bf16x4 bb = *(const bf16x4*)&bob[col];
        f32x4 o;
        for (int r = 0; r < 4; r++) o[r] = acc[nt][r] + (float)bb[r];
        *(f32x4*)&outp[(size_t)row * D_ + col] = o;
    }
}

// ---------------------------------------------------------------------------
extern "C" void kernel_launch(void* const* d_in, const int* in_sizes, int n_in,
                              void* d_out, int out_size, void* d_ws, size_t ws_size,
                              hipStream_t stream)
{
    const void* x  = d_in[0];
    const void* Wq = d_in[1];
    const void* bq = d_in[2];
    const void* Wk = d_in[3];
    const void* bk = d_in[4];
    const void* Wv = d_in[5];
    const void* bv = d_in[6];
    const void* Wo = d_in[7];
    const void* bo = d_in[8];
    float* out = (float*)d_out;

    char* ws = (char*)d_ws;
    bf16* qkv  = (bf16*)ws;                          // 201326592 B
    bf16* WT   = (bf16*)(ws + 201326592);            // 3145728 B
    bf16* WoT  = (bf16*)(ws + 204472320);            // 1048576 B
    bf16* xb   = (bf16*)(ws + 205520896);            // 8388608 B
    bf16* bqkv = (bf16*)(ws + 213909504);            // 12288 B
    bf16* bob  = (bf16*)(ws + 213921792);            // 512 B
    // P (16384*64 f32 = 4 MB) reuses the xb region: xb is dead after
    // proj_gemm, and attn_score runs strictly after it on the same stream.
    float* Pbuf = (float*)xb;

    prep<<<6169, 256, 0, stream>>>(x, Wq, bq, Wk, bk, Wv, bv, Wo, bo,
                                   xb, WT, WoT, bqkv, bob);
    proj_gemm<<<dim3(48, 128), 256, 0, stream>>>(xb, WT, bqkv, qkv);
    attn_score<<<512, 256, 0, stream>>>(qkv, Pbuf);
    out_fused<<<512, 256, 0, stream>>>(qkv, WoT, Pbuf, bob, out);
}